// Round 1
// baseline (257.433 us; speedup 1.0000x reference)
//
#include <hip/hip_runtime.h>
#include <stdint.h>

typedef float f32x4 __attribute__((ext_vector_type(4)));
typedef short s16x8 __attribute__((ext_vector_type(8)));
typedef short s16x4 __attribute__((ext_vector_type(4)));

__device__ __forceinline__ short f2bf(float f){
  union { float f; unsigned u; } v; v.f = f;
  unsigned r = v.u + 0x7FFFu + ((v.u >> 16) & 1u);
  return (short)(r >> 16);
}
__device__ __forceinline__ float bf2f(short h){
  union { unsigned u; float f; } v; v.u = ((unsigned)(unsigned short)h) << 16;
  return v.f;
}

// ---------- elementwise: o = bf16(a+b), 8 elems/thread ----------
__global__ void k_addcvt(const float* __restrict__ a, const float* __restrict__ b,
                         short* __restrict__ o){
  long i = (long)blockIdx.x * blockDim.x + threadIdx.x;
  const f32x4* a4 = (const f32x4*)a;
  const f32x4* b4 = (const f32x4*)b;
  f32x4 x0 = a4[2*i], x1 = a4[2*i+1];
  f32x4 y0 = b4[2*i], y1 = b4[2*i+1];
  s16x8 r;
  #pragma unroll
  for (int j=0;j<4;j++){ r[j] = f2bf(x0[j]+y0[j]); r[j+4] = f2bf(x1[j]+y1[j]); }
  *(s16x8*)(o + i*8) = r;
}

// ---------- fp32 -> bf16 convert, 4/thread ----------
__global__ void k_cvt(const float* __restrict__ in, short* __restrict__ out){
  long i = (long)blockIdx.x * blockDim.x + threadIdx.x;
  f32x4 v = ((const f32x4*)in)[i];
  s16x4 r;
  #pragma unroll
  for (int j=0;j<4;j++) r[j] = f2bf(v[j]);
  *(s16x4*)(out + i*4) = r;
}

// ---------- transpose + convert: out[c][r] = bf16(in[r][c]) ----------
__global__ void k_transcvt(const float* __restrict__ in, short* __restrict__ out,
                           int rows, int cols){
  __shared__ float tile[32][33];
  int c0 = blockIdx.x*32, r0 = blockIdx.y*32;
  #pragma unroll
  for (int i=threadIdx.y; i<32; i+=8)
    tile[i][threadIdx.x] = in[(long)(r0+i)*cols + c0 + threadIdx.x];
  __syncthreads();
  #pragma unroll
  for (int i=threadIdx.y; i<32; i+=8)
    out[(long)(c0+i)*rows + r0 + threadIdx.x] = f2bf(tile[threadIdx.x][i]);
}

// ---------- bias1: bc[z*1024+n] = dot(out_w_z[n,:], bv_z) + ob_z[n] ----------
__global__ void k_bias1(const float* __restrict__ wt, const float* __restrict__ bvt, const float* __restrict__ obt,
                        const float* __restrict__ wi, const float* __restrict__ bvi, const float* __restrict__ obi,
                        float* __restrict__ bc){
  int z = blockIdx.y;
  const float* w  = z ? wi  : wt;
  const float* bv = z ? bvi : bvt;
  const float* ob = z ? obi : obt;
  int n = blockIdx.x*4 + (threadIdx.x>>6);
  int lane = threadIdx.x & 63;
  const float* row = w + (long)n*1024;
  float acc = 0.f;
  for (int j=lane; j<1024; j+=64) acc += row[j]*bv[j];
  #pragma unroll
  for (int m=32;m;m>>=1) acc += __shfl_xor(acc, m, 64);
  if (lane==0) bc[z*1024+n] = acc + ob[n];
}

// ---------- bias2: b_all[1024+n] = dot(bf16 Wc[n,:], fuse_b) + bc[n], n in [0,2048) ----------
__global__ void k_bias2(const short* __restrict__ Wc, const float* __restrict__ fuse_b,
                        const float* __restrict__ bc, float* __restrict__ b_all){
  int n = blockIdx.x*4 + (threadIdx.x>>6);
  int lane = threadIdx.x & 63;
  const short* row = Wc + (long)n*1024;
  float acc = 0.f;
  for (int j=lane; j<1024; j+=64) acc += bf2f(row[j])*fuse_b[j];
  #pragma unroll
  for (int m=32;m;m>>=1) acc += __shfl_xor(acc, m, 64);
  if (lane==0) b_all[1024+n] = acc + bc[n];
}

__global__ void k_copy(const float* __restrict__ src, float* __restrict__ dst, int n){
  int i = blockIdx.x*blockDim.x + threadIdx.x;
  if (i<n) dst[i] = src[i];
}

// ---------- NT GEMM: C[m][n] = sum_k A[m][k]*B[n][k], bf16 in, m97 structure ----------
#define GLDS(src, dst) __builtin_amdgcn_global_load_lds( \
    (const __attribute__((address_space(1))) void*)(src), \
    (__attribute__((address_space(3))) void*)(dst), 16, 0, 0)

// MODE 0: bf16 C row-major (M x N), no bias.
// MODE 1: fp32 out, +bias[gn], scatter: n/1024 region -> {fused:2BD, text:0, image:BD}
template<int MODE>
__global__ __launch_bounds__(256, 2)
void gemm_nt(const short* __restrict__ Abase, const short* __restrict__ Bbase,
             void* __restrict__ Cbase, const float* __restrict__ bias,
             int M, int N, int K, long zA, long zB, long zC)
{
  __shared__ __align__(16) short ldsA[128*32];
  __shared__ __align__(16) short ldsB[128*32];
  const short* A = Abase + (long)blockIdx.z * zA;
  const short* B = Bbase + (long)blockIdx.z * zB;
  const int m0 = blockIdx.x * 128;
  const int n0 = blockIdx.y * 128;
  const int tid = threadIdx.x;
  const int lane = tid & 63;
  const int wv = tid >> 6;
  const int wm = wv >> 1, wn = wv & 1;

  f32x4 acc[4][4];
  #pragma unroll
  for (int i=0;i<4;i++)
    #pragma unroll
    for (int j=0;j<4;j++) acc[i][j] = (f32x4){0.f,0.f,0.f,0.f};

  const int bo0 = wv*1024 + lane*16;   // byte offset within 8KB tile (lane-resolved)
  const int bo1 = bo0 + 4096;
  const int r0 = bo0 >> 6, c0 = bo0 & 63;
  const int r1 = bo1 >> 6, c1 = bo1 & 63;
  const long rsb = (long)K * 2;        // row stride bytes

  const char* Ab = (const char*)A;
  const char* Bb = (const char*)B;
  char* lA = (char*)&ldsA[0];
  char* lB = (char*)&ldsB[0];

  const int nkt = K >> 5;
  for (int kt = 0; kt < nkt; ++kt) {
    const long kb = (long)kt * 64;
    GLDS(Ab + (long)(m0 + r0)*rsb + kb + c0, lA + wv*1024);
    GLDS(Ab + (long)(m0 + r1)*rsb + kb + c1, lA + 4096 + wv*1024);
    GLDS(Bb + (long)(n0 + r0)*rsb + kb + c0, lB + wv*1024);
    GLDS(Bb + (long)(n0 + r1)*rsb + kb + c1, lB + 4096 + wv*1024);
    __syncthreads();

    s16x8 af[4], bfv[4];
    #pragma unroll
    for (int i=0;i<4;i++)
      af[i] = *(const s16x8*)(lA + (wm*64 + i*16 + (lane&15))*64 + (lane>>4)*16);
    #pragma unroll
    for (int j=0;j<4;j++)
      bfv[j] = *(const s16x8*)(lB + (wn*64 + j*16 + (lane&15))*64 + (lane>>4)*16);

    #pragma unroll
    for (int i=0;i<4;i++)
      #pragma unroll
      for (int j=0;j<4;j++)
        acc[i][j] = __builtin_amdgcn_mfma_f32_16x16x32_bf16(af[i], bfv[j], acc[i][j], 0, 0, 0);
    __syncthreads();
  }

  if (MODE == 0) {
    short* C = (short*)Cbase + (long)blockIdx.z * zC;
    #pragma unroll
    for (int j=0;j<4;j++){
      int gn = n0 + wn*64 + j*16 + (lane&15);
      #pragma unroll
      for (int i=0;i<4;i++){
        int gmb = m0 + wm*64 + i*16 + ((lane>>4)*4);
        #pragma unroll
        for (int r=0;r<4;r++)
          C[(long)(gmb+r)*N + gn] = f2bf(acc[i][j][r]);
      }
    }
  } else {
    float* O = (float*)Cbase;
    const long BD = 16384L * 1024L;
    #pragma unroll
    for (int j=0;j<4;j++){
      int gn = n0 + wn*64 + j*16 + (lane&15);
      float bb = bias[gn];
      int region = gn >> 10;
      long rbase = (region==0) ? 2*BD : ((region==1) ? 0L : BD);
      int col = gn & 1023;
      #pragma unroll
      for (int i=0;i<4;i++){
        int gmb = m0 + wm*64 + i*16 + ((lane>>4)*4);
        #pragma unroll
        for (int r=0;r<4;r++)
          O[rbase + (long)(gmb+r)*1024 + col] = acc[i][j][r] + bb;
      }
    }
  }
}

extern "C" void kernel_launch(void* const* d_in, const int* in_sizes, int n_in,
                              void* d_out, int out_size, void* d_ws, size_t ws_size,
                              hipStream_t stream) {
  const float* text    = (const float*)d_in[0];
  const float* image   = (const float*)d_in[1];
  const float* fuse_w  = (const float*)d_in[2];
  const float* fuse_b  = (const float*)d_in[3];
  const float* t_in_w  = (const float*)d_in[4];
  const float* t_in_b  = (const float*)d_in[5];
  const float* t_out_w = (const float*)d_in[6];
  const float* t_out_b = (const float*)d_in[7];
  const float* i_in_w  = (const float*)d_in[8];
  const float* i_in_b  = (const float*)d_in[9];
  const float* i_out_w = (const float*)d_in[10];
  const float* i_out_b = (const float*)d_in[11];
  float* out = (float*)d_out;

  const long DD = 1024L*1024L;
  char* ws = (char*)d_ws;
  short* s_bf    = (short*)ws; ws += 16384L*1024*2;
  short* W_all   = (short*)ws; ws += 3*DD*2;      // rows: [fuse_w; Wt2; Wi2]
  short* wvT     = (short*)ws; ws += 2*DD*2;      // [wvT_t; wvT_i]
  short* fuse_wT = (short*)ws; ws += DD*2;
  short* outw_st = (short*)ws; ws += 2*DD*2;      // [t_out_w; i_out_w] bf16
  short* Wc_st   = (short*)ws; ws += 2*DD*2;      // [Wc_t; Wc_i]
  float* bc      = (float*)ws; ws += 2048*4;
  float* b_all   = (float*)ws; ws += 3072*4;

  dim3 tb(32,8);

  // prep
  k_addcvt<<<8192, 256, 0, stream>>>(text, image, s_bf);
  k_cvt<<<1024, 256, 0, stream>>>(fuse_w, W_all);
  k_cvt<<<1024, 256, 0, stream>>>(t_out_w, outw_st);
  k_cvt<<<1024, 256, 0, stream>>>(i_out_w, outw_st + DD);
  k_transcvt<<<dim3(32,32), tb, 0, stream>>>(t_in_w + 2*DD, wvT,      1024, 1024);
  k_transcvt<<<dim3(32,32), tb, 0, stream>>>(i_in_w + 2*DD, wvT + DD, 1024, 1024);
  k_transcvt<<<dim3(32,32), tb, 0, stream>>>(fuse_w, fuse_wT, 1024, 1024);
  k_bias1<<<dim3(256,2), 256, 0, stream>>>(t_out_w, t_in_b + 2048, t_out_b,
                                           i_out_w, i_in_b + 2048, i_out_b, bc);

  // Wc_z = out_w_z @ wv_z  (NT: A=out_w, B=wvT)
  gemm_nt<0><<<dim3(8,8,2), 256, 0, stream>>>(outw_st, wvT, Wc_st, nullptr,
                                              1024, 1024, 1024, DD, DD, DD);
  // b_all[1024..3072) = Wc @ fuse_b + bc
  k_bias2<<<512, 256, 0, stream>>>(Wc_st, fuse_b, bc, b_all);
  k_copy<<<4, 256, 0, stream>>>(fuse_b, b_all, 1024);
  // [Wt2; Wi2] = Wc_st @ fuse_w (NT: B=fuse_wT) -> W_all rows 1024..3071
  gemm_nt<0><<<dim3(16,8,1), 256, 0, stream>>>(Wc_st, fuse_wT, W_all + DD, nullptr,
                                               2048, 1024, 1024, 0, 0, 0);
  // main: C = s @ W_all.T + b_all, scatter into d_out
  gemm_nt<1><<<dim3(128,24,1), 256, 0, stream>>>(s_bf, W_all, out, b_all,
                                                 16384, 3072, 1024, 0, 0, 0);
}

// Round 2
// 247.407 us; speedup vs baseline: 1.0405x; 1.0405x over previous
//
#include <hip/hip_runtime.h>
#include <stdint.h>

typedef float f32x4 __attribute__((ext_vector_type(4)));
typedef short s16x8 __attribute__((ext_vector_type(8)));
typedef short s16x4 __attribute__((ext_vector_type(4)));

__device__ __forceinline__ short f2bf(float f){
  union { float f; unsigned u; } v; v.f = f;
  unsigned r = v.u + 0x7FFFu + ((v.u >> 16) & 1u);
  return (short)(r >> 16);
}
__device__ __forceinline__ float bf2f(short h){
  union { unsigned u; float f; } v; v.u = ((unsigned)(unsigned short)h) << 16;
  return v.f;
}

// ---------- elementwise: o = bf16(a+b), 8 elems/thread ----------
__global__ void k_addcvt(const float* __restrict__ a, const float* __restrict__ b,
                         short* __restrict__ o){
  long i = (long)blockIdx.x * blockDim.x + threadIdx.x;
  const f32x4* a4 = (const f32x4*)a;
  const f32x4* b4 = (const f32x4*)b;
  f32x4 x0 = a4[2*i], x1 = a4[2*i+1];
  f32x4 y0 = b4[2*i], y1 = b4[2*i+1];
  s16x8 r;
  #pragma unroll
  for (int j=0;j<4;j++){ r[j] = f2bf(x0[j]+y0[j]); r[j+4] = f2bf(x1[j]+y1[j]); }
  *(s16x8*)(o + i*8) = r;
}

// ---------- fp32 -> bf16 convert, 4/thread ----------
__global__ void k_cvt(const float* __restrict__ in, short* __restrict__ out){
  long i = (long)blockIdx.x * blockDim.x + threadIdx.x;
  f32x4 v = ((const f32x4*)in)[i];
  s16x4 r;
  #pragma unroll
  for (int j=0;j<4;j++) r[j] = f2bf(v[j]);
  *(s16x4*)(out + i*4) = r;
}

// ---------- transpose + convert: out[c][r] = bf16(in[r][c]) ----------
__global__ void k_transcvt(const float* __restrict__ in, short* __restrict__ out,
                           int rows, int cols){
  __shared__ float tile[32][33];
  int c0 = blockIdx.x*32, r0 = blockIdx.y*32;
  #pragma unroll
  for (int i=threadIdx.y; i<32; i+=8)
    tile[i][threadIdx.x] = in[(long)(r0+i)*cols + c0 + threadIdx.x];
  __syncthreads();
  #pragma unroll
  for (int i=threadIdx.y; i<32; i+=8)
    out[(long)(c0+i)*rows + r0 + threadIdx.x] = f2bf(tile[threadIdx.x][i]);
}

// ---------- bias1 ----------
__global__ void k_bias1(const float* __restrict__ wt, const float* __restrict__ bvt, const float* __restrict__ obt,
                        const float* __restrict__ wi, const float* __restrict__ bvi, const float* __restrict__ obi,
                        float* __restrict__ bc){
  int z = blockIdx.y;
  const float* w  = z ? wi  : wt;
  const float* bv = z ? bvi : bvt;
  const float* ob = z ? obi : obt;
  int n = blockIdx.x*4 + (threadIdx.x>>6);
  int lane = threadIdx.x & 63;
  const float* row = w + (long)n*1024;
  float acc = 0.f;
  for (int j=lane; j<1024; j+=64) acc += row[j]*bv[j];
  #pragma unroll
  for (int m=32;m;m>>=1) acc += __shfl_xor(acc, m, 64);
  if (lane==0) bc[z*1024+n] = acc + ob[n];
}

// ---------- bias2 ----------
__global__ void k_bias2(const short* __restrict__ Wc, const float* __restrict__ fuse_b,
                        const float* __restrict__ bc, float* __restrict__ b_all){
  int n = blockIdx.x*4 + (threadIdx.x>>6);
  int lane = threadIdx.x & 63;
  const short* row = Wc + (long)n*1024;
  float acc = 0.f;
  for (int j=lane; j<1024; j+=64) acc += bf2f(row[j])*fuse_b[j];
  #pragma unroll
  for (int m=32;m;m>>=1) acc += __shfl_xor(acc, m, 64);
  if (lane==0) b_all[1024+n] = acc + bc[n];
}

__global__ void k_copy(const float* __restrict__ src, float* __restrict__ dst, int n){
  int i = blockIdx.x*blockDim.x + threadIdx.x;
  if (i<n) dst[i] = src[i];
}

#define GLDS(src, dst) __builtin_amdgcn_global_load_lds( \
    (const __attribute__((address_space(1))) void*)(src), \
    (__attribute__((address_space(3))) void*)(dst), 16, 0, 0)

// ---------- small NT GEMM (128x128 tile, m97 structure): C bf16 = A@B^T ----------
__global__ __launch_bounds__(256, 2)
void gemm_nt_small(const short* __restrict__ Abase, const short* __restrict__ Bbase,
                   short* __restrict__ Cbase,
                   int M, int N, int K, long zA, long zB, long zC)
{
  __shared__ __align__(16) short ldsA[128*32];
  __shared__ __align__(16) short ldsB[128*32];
  const short* A = Abase + (long)blockIdx.z * zA;
  const short* B = Bbase + (long)blockIdx.z * zB;
  const int m0 = blockIdx.x * 128;
  const int n0 = blockIdx.y * 128;
  const int tid = threadIdx.x;
  const int lane = tid & 63;
  const int wv = tid >> 6;
  const int wm = wv >> 1, wn = wv & 1;

  f32x4 acc[4][4];
  #pragma unroll
  for (int i=0;i<4;i++)
    #pragma unroll
    for (int j=0;j<4;j++) acc[i][j] = (f32x4){0.f,0.f,0.f,0.f};

  const int bo0 = wv*1024 + lane*16;
  const int bo1 = bo0 + 4096;
  const int r0 = bo0 >> 6, c0 = bo0 & 63;
  const int r1 = bo1 >> 6, c1 = bo1 & 63;
  const long rsb = (long)K * 2;

  const char* Ab = (const char*)A;
  const char* Bb = (const char*)B;
  char* lA = (char*)&ldsA[0];
  char* lB = (char*)&ldsB[0];

  const int nkt = K >> 5;
  for (int kt = 0; kt < nkt; ++kt) {
    const long kb = (long)kt * 64;
    GLDS(Ab + (long)(m0 + r0)*rsb + kb + c0, lA + wv*1024);
    GLDS(Ab + (long)(m0 + r1)*rsb + kb + c1, lA + 4096 + wv*1024);
    GLDS(Bb + (long)(n0 + r0)*rsb + kb + c0, lB + wv*1024);
    GLDS(Bb + (long)(n0 + r1)*rsb + kb + c1, lB + 4096 + wv*1024);
    __syncthreads();

    s16x8 af[4], bfv[4];
    #pragma unroll
    for (int i=0;i<4;i++)
      af[i] = *(const s16x8*)(lA + (wm*64 + i*16 + (lane&15))*64 + (lane>>4)*16);
    #pragma unroll
    for (int j=0;j<4;j++)
      bfv[j] = *(const s16x8*)(lB + (wn*64 + j*16 + (lane&15))*64 + (lane>>4)*16);

    #pragma unroll
    for (int i=0;i<4;i++)
      #pragma unroll
      for (int j=0;j<4;j++)
        acc[i][j] = __builtin_amdgcn_mfma_f32_16x16x32_bf16(af[i], bfv[j], acc[i][j], 0, 0, 0);
    __syncthreads();
  }

  short* C = Cbase + (long)blockIdx.z * zC;
  #pragma unroll
  for (int j=0;j<4;j++){
    int gn = n0 + wn*64 + j*16 + (lane&15);
    #pragma unroll
    for (int i=0;i<4;i++){
      int gmb = m0 + wm*64 + i*16 + ((lane>>4)*4);
      #pragma unroll
      for (int r=0;r<4;r++)
        C[(long)(gmb+r)*N + gn] = f2bf(acc[i][j][r]);
    }
  }
}

// ---------- main NT GEMM: 256x256 tile, BK=64, 8-phase schedule (T2+T3+T4+T5) ----------
// LDS map (bytes): A-buf0 @0, A-buf1 @32768, B-buf0 @65536, B-buf1 @98304.
// st_16x32 swizzle: byte ^= ((byte>>9)&1)<<5, applied within each 32KiB tile region.
// Stage slots per iteration (compute tile t ph1-4 from buf0, t+1 ph5-8 from buf1):
//   ph1: A0(t+1)->A1   ph2: A1(t+1)->A1   ph3: B0(t+2)->B0   ph4: B1(t+2)->B0  [vmcnt(4)]
//   ph5: A0(t+2)->A0   ph6: A1(t+2)->A0   ph7: B0(t+3)->B1   ph8: B1(t+3)->B1  [vmcnt(4)]
// Each stage-issue follows the barrier that ends the last phase reading its target region.
#define MFMA16 __builtin_amdgcn_mfma_f32_16x16x32_bf16
#define VMW4 asm volatile("s_waitcnt vmcnt(4)" ::: "memory")
#define VMW0 asm volatile("s_waitcnt vmcnt(0)" ::: "memory")
#define NOSTAGE ((void)0)

#define PHASE(BUF, Q, STAGE_STMT, VM) { \
  if ((Q)==0) { \
    _Pragma("unroll") \
    for (int j=0;j<4;j++){ bfr[j][0]=ldB(BUF,j,0); bfr[j][1]=ldB(BUF,j,1);} \
  } \
  s16x8 aq0 = ldA(BUF, 2*(Q), 0),   aq1 = ldA(BUF, 2*(Q), 1); \
  s16x8 aq2 = ldA(BUF, 2*(Q)+1, 0), aq3 = ldA(BUF, 2*(Q)+1, 1); \
  STAGE_STMT; \
  asm volatile("" ::: "memory"); \
  __builtin_amdgcn_s_barrier(); \
  asm volatile("s_waitcnt lgkmcnt(0)" ::: "memory"); \
  __builtin_amdgcn_s_setprio(1); \
  _Pragma("unroll") \
  for (int j=0;j<4;j++){ \
    acc[2*(Q)][j]   = MFMA16(aq0, bfr[j][0], acc[2*(Q)][j],   0,0,0); \
    acc[2*(Q)][j]   = MFMA16(aq1, bfr[j][1], acc[2*(Q)][j],   0,0,0); \
    acc[2*(Q)+1][j] = MFMA16(aq2, bfr[j][0], acc[2*(Q)+1][j], 0,0,0); \
    acc[2*(Q)+1][j] = MFMA16(aq3, bfr[j][1], acc[2*(Q)+1][j], 0,0,0); \
  } \
  __builtin_amdgcn_s_setprio(0); \
  VM; \
  asm volatile("" ::: "memory"); \
  __builtin_amdgcn_s_barrier(); \
}

__global__ __launch_bounds__(512, 2)
void gemm_main(const short* __restrict__ A, const short* __restrict__ B,
               float* __restrict__ O, const float* __restrict__ bias,
               int M, int N, int K)
{
  __shared__ __align__(16) char lds[131072];

  const int nbn = N >> 8;
  const int nwg = (M >> 8) * nbn;
  const int cpx = nwg >> 3;
  int bid = blockIdx.x;
  int swz = (bid & 7) * cpx + (bid >> 3);
  const int m0 = (swz / nbn) << 8;
  const int n0 = (swz % nbn) << 8;

  const int tid  = threadIdx.x;
  const int lane = tid & 63;
  const int wid  = tid >> 6;
  const int wm   = wid >> 2;   // 0..1
  const int wn   = wid & 3;    // 0..3
  const long rsb = (long)K * 2;
  const char* Ab = (const char*)A;
  const char* Bb = (const char*)B;

  f32x4 acc[8][4];
  #pragma unroll
  for (int i=0;i<8;i++)
    #pragma unroll
    for (int j=0;j<4;j++) acc[i][j] = (f32x4){0.f,0.f,0.f,0.f};

  // Precompute per-lane stage source offsets (H in {0,1} x sub in {0,1}).
  // chunk c = H*1024 + sub*512 + wid*64 + lane; inverse-swizzled logical chunk
  // q = c ^ (((c>>5)&1)<<1); source row = q>>3, col bytes = (q&7)*16.
  long srow[2][2]; int scol[2][2]; int sdst[2][2];
  #pragma unroll
  for (int H=0;H<2;H++)
    #pragma unroll
    for (int sb=0;sb<2;sb++){
      int c = H*1024 + sb*512 + wid*64 + lane;
      int q = c ^ (((c>>5)&1)<<1);
      srow[H][sb] = (long)(q >> 3);
      scol[H][sb] = (q & 7) << 4;
      sdst[H][sb] = (H*1024 + sb*512 + wid*64) << 4;  // wave-uniform LDS byte base
    }

  auto stage = [&](const char* P, int tr0, int s /*K-tile*/, int RB, int H){
    const long ktb = (long)s << 7;  // s * 64 elems * 2B
    GLDS(P + ((long)tr0 + srow[H][0])*rsb + ktb + scol[H][0], lds + RB + sdst[H][0]);
    GLDS(P + ((long)tr0 + srow[H][1])*rsb + ktb + scol[H][1], lds + RB + sdst[H][1]);
  };

  const int swx = ((lane >> 2) & 1) << 5;  // row bit2 == lane bit2 for all frags
  auto ldA = [&](int buf, int i, int ks) -> s16x8 {
    int off = (wm*128 + i*16 + (lane&15))*128 + ks*64 + ((lane>>4)<<4);
    off ^= swx;
    return *(const s16x8*)(lds + (buf<<15) + off);
  };
  auto ldB = [&](int buf, int j, int ks) -> s16x8 {
    int off = (wn*64 + j*16 + (lane&15))*128 + ks*64 + ((lane>>4)<<4);
    off ^= swx;
    return *(const s16x8*)(lds + 65536 + (buf<<15) + off);
  };

  s16x8 bfr[4][2];
  const int nkt = K >> 6;  // 64-wide K-tiles (assume even, >= 4)

  // Prologue: stage B(t0), A(t0), B(t1); wait all but B(t1) halves.
  stage(Bb, n0, 0, 65536, 0); stage(Bb, n0, 0, 65536, 1);
  stage(Ab, m0, 0, 0,     0); stage(Ab, m0, 0, 0,     1);
  stage(Bb, n0, 1, 98304, 0); stage(Bb, n0, 1, 98304, 1);
  VMW4;
  asm volatile("" ::: "memory");
  __builtin_amdgcn_s_barrier();

  for (int it = 0; it < (nkt>>1) - 1; ++it) {
    const int t = it*2;
    PHASE(0, 0, stage(Ab, m0, t+1, 32768, 0), NOSTAGE)
    PHASE(0, 1, stage(Ab, m0, t+1, 32768, 1), NOSTAGE)
    PHASE(0, 2, stage(Bb, n0, t+2, 65536, 0), NOSTAGE)
    PHASE(0, 3, stage(Bb, n0, t+2, 65536, 1), VMW4)
    PHASE(1, 0, stage(Ab, m0, t+2, 0,     0), NOSTAGE)
    PHASE(1, 1, stage(Ab, m0, t+2, 0,     1), NOSTAGE)
    PHASE(1, 2, stage(Bb, n0, t+3, 98304, 0), NOSTAGE)
    PHASE(1, 3, stage(Bb, n0, t+3, 98304, 1), VMW4)
  }
  {
    const int t = nkt - 2;
    PHASE(0, 0, stage(Ab, m0, t+1, 32768, 0), NOSTAGE)
    PHASE(0, 1, stage(Ab, m0, t+1, 32768, 1), NOSTAGE)
    PHASE(0, 2, NOSTAGE, NOSTAGE)
    PHASE(0, 3, NOSTAGE, VMW0)
    PHASE(1, 0, NOSTAGE, NOSTAGE)
    PHASE(1, 1, NOSTAGE, NOSTAGE)
    PHASE(1, 2, NOSTAGE, NOSTAGE)
    PHASE(1, 3, NOSTAGE, NOSTAGE)
  }

  // Epilogue: fp32 + bias, scatter by output region (text | image | fused).
  const long BD = (long)M * 1024L;
  #pragma unroll
  for (int j=0;j<4;j++){
    int gn = n0 + wn*64 + j*16 + (lane&15);
    float bb = bias[gn];
    int region = gn >> 10;
    long rbase = (region==0) ? 2*BD : ((region==1) ? 0L : BD);
    int col = gn & 1023;
    #pragma unroll
    for (int i=0;i<8;i++){
      int gr = m0 + wm*128 + i*16 + ((lane>>4)<<2);
      #pragma unroll
      for (int r=0;r<4;r++)
        O[rbase + (long)(gr+r)*1024 + col] = acc[i][j][r] + bb;
    }
  }
}

extern "C" void kernel_launch(void* const* d_in, const int* in_sizes, int n_in,
                              void* d_out, int out_size, void* d_ws, size_t ws_size,
                              hipStream_t stream) {
  const float* text    = (const float*)d_in[0];
  const float* image   = (const float*)d_in[1];
  const float* fuse_w  = (const float*)d_in[2];
  const float* fuse_b  = (const float*)d_in[3];
  const float* t_in_w  = (const float*)d_in[4];
  const float* t_in_b  = (const float*)d_in[5];
  const float* t_out_w = (const float*)d_in[6];
  const float* t_out_b = (const float*)d_in[7];
  const float* i_in_w  = (const float*)d_in[8];
  const float* i_in_b  = (const float*)d_in[9];
  const float* i_out_w = (const float*)d_in[10];
  const float* i_out_b = (const float*)d_in[11];
  float* out = (float*)d_out;

  const long DD = 1024L*1024L;
  char* ws = (char*)d_ws;
  short* s_bf    = (short*)ws; ws += 16384L*1024*2;
  short* W_all   = (short*)ws; ws += 3*DD*2;      // rows: [fuse_w; Wt2; Wi2]
  short* wvT     = (short*)ws; ws += 2*DD*2;      // [wvT_t; wvT_i]
  short* fuse_wT = (short*)ws; ws += DD*2;
  short* outw_st = (short*)ws; ws += 2*DD*2;      // [t_out_w; i_out_w] bf16
  short* Wc_st   = (short*)ws; ws += 2*DD*2;      // [Wc_t; Wc_i]
  float* bc      = (float*)ws; ws += 2048*4;
  float* b_all   = (float*)ws; ws += 3072*4;

  dim3 tb(32,8);

  // prep
  k_addcvt<<<8192, 256, 0, stream>>>(text, image, s_bf);
  k_cvt<<<1024, 256, 0, stream>>>(fuse_w, W_all);
  k_cvt<<<1024, 256, 0, stream>>>(t_out_w, outw_st);
  k_cvt<<<1024, 256, 0, stream>>>(i_out_w, outw_st + DD);
  k_transcvt<<<dim3(32,32), tb, 0, stream>>>(t_in_w + 2*DD, wvT,      1024, 1024);
  k_transcvt<<<dim3(32,32), tb, 0, stream>>>(i_in_w + 2*DD, wvT + DD, 1024, 1024);
  k_transcvt<<<dim3(32,32), tb, 0, stream>>>(fuse_w, fuse_wT, 1024, 1024);
  k_bias1<<<dim3(256,2), 256, 0, stream>>>(t_out_w, t_in_b + 2048, t_out_b,
                                           i_out_w, i_in_b + 2048, i_out_b, bc);

  // Wc_z = out_w_z @ wv_z
  gemm_nt_small<<<dim3(8,8,2), 256, 0, stream>>>(outw_st, wvT, Wc_st,
                                                 1024, 1024, 1024, DD, DD, DD);
  // b_all[1024..3072) = Wc @ fuse_b + bc ; b_all[0..1024) = fuse_b
  k_bias2<<<512, 256, 0, stream>>>(Wc_st, fuse_b, bc, b_all);
  k_copy<<<4, 256, 0, stream>>>(fuse_b, b_all, 1024);
  // [Wt2; Wi2] = Wc @ fuse_w
  gemm_nt_small<<<dim3(16,8,1), 256, 0, stream>>>(Wc_st, fuse_wT, W_all + DD,
                                                  2048, 1024, 1024, 0, 0, 0);
  // main: C = s @ W_all.T + b_all, scatter into d_out
  gemm_main<<<dim3(768), 512, 0, stream>>>(s_bf, W_all, out, b_all, 16384, 3072, 1024);
}

// Round 3
// 232.587 us; speedup vs baseline: 1.1068x; 1.0637x over previous
//
#include <hip/hip_runtime.h>
#include <stdint.h>

typedef float f32x4 __attribute__((ext_vector_type(4)));
typedef short s16x8 __attribute__((ext_vector_type(8)));
typedef short s16x4 __attribute__((ext_vector_type(4)));

__device__ __forceinline__ short f2bf(float f){
  union { float f; unsigned u; } v; v.f = f;
  unsigned r = v.u + 0x7FFFu + ((v.u >> 16) & 1u);
  return (short)(r >> 16);
}
__device__ __forceinline__ float bf2f(short h){
  union { unsigned u; float f; } v; v.u = ((unsigned)(unsigned short)h) << 16;
  return v.f;
}

// ---------- elementwise: o = bf16(a+b), 8 elems/thread ----------
__global__ void k_addcvt(const float* __restrict__ a, const float* __restrict__ b,
                         short* __restrict__ o){
  long i = (long)blockIdx.x * blockDim.x + threadIdx.x;
  const f32x4* a4 = (const f32x4*)a;
  const f32x4* b4 = (const f32x4*)b;
  f32x4 x0 = a4[2*i], x1 = a4[2*i+1];
  f32x4 y0 = b4[2*i], y1 = b4[2*i+1];
  s16x8 r;
  #pragma unroll
  for (int j=0;j<4;j++){ r[j] = f2bf(x0[j]+y0[j]); r[j+4] = f2bf(x1[j]+y1[j]); }
  *(s16x8*)(o + i*8) = r;
}

// ---------- fp32 -> bf16 convert, 3 tensors in one launch ----------
__global__ void k_cvt3(const float* __restrict__ s0, short* __restrict__ d0,
                       const float* __restrict__ s1, short* __restrict__ d1,
                       const float* __restrict__ s2, short* __restrict__ d2){
  int z = blockIdx.y;
  const float* in = (z==0) ? s0 : ((z==1) ? s1 : s2);
  short* out      = (z==0) ? d0 : ((z==1) ? d1 : d2);
  long i = (long)blockIdx.x * blockDim.x + threadIdx.x;
  f32x4 v = ((const f32x4*)in)[i];
  s16x4 r;
  #pragma unroll
  for (int j=0;j<4;j++) r[j] = f2bf(v[j]);
  *(s16x4*)(out + i*4) = r;
}

// ---------- transpose + convert, 3 tensors (1024x1024 each) ----------
__global__ void k_transcvt3(const float* __restrict__ s0, short* __restrict__ d0,
                            const float* __restrict__ s1, short* __restrict__ d1,
                            const float* __restrict__ s2, short* __restrict__ d2){
  int z = blockIdx.z;
  const float* in = (z==0) ? s0 : ((z==1) ? s1 : s2);
  short* out      = (z==0) ? d0 : ((z==1) ? d1 : d2);
  __shared__ float tile[32][33];
  int c0 = blockIdx.x*32, r0 = blockIdx.y*32;
  #pragma unroll
  for (int i=threadIdx.y; i<32; i+=8)
    tile[i][threadIdx.x] = in[(long)(r0+i)*1024 + c0 + threadIdx.x];
  __syncthreads();
  #pragma unroll
  for (int i=threadIdx.y; i<32; i+=8)
    out[(long)(c0+i)*1024 + r0 + threadIdx.x] = f2bf(tile[threadIdx.x][i]);
}

// ---------- bias1 ----------
__global__ void k_bias1(const float* __restrict__ wt, const float* __restrict__ bvt, const float* __restrict__ obt,
                        const float* __restrict__ wi, const float* __restrict__ bvi, const float* __restrict__ obi,
                        float* __restrict__ bc){
  int z = blockIdx.y;
  const float* w  = z ? wi  : wt;
  const float* bv = z ? bvi : bvt;
  const float* ob = z ? obi : obt;
  int n = blockIdx.x*4 + (threadIdx.x>>6);
  int lane = threadIdx.x & 63;
  const float* row = w + (long)n*1024;
  float acc = 0.f;
  for (int j=lane; j<1024; j+=64) acc += row[j]*bv[j];
  #pragma unroll
  for (int m=32;m;m>>=1) acc += __shfl_xor(acc, m, 64);
  if (lane==0) bc[z*1024+n] = acc + ob[n];
}

// ---------- bias2 + fuse_b copy folded in (blocks 512..515 copy) ----------
__global__ void k_bias2c(const short* __restrict__ Wc, const float* __restrict__ fuse_b,
                         const float* __restrict__ bc, float* __restrict__ b_all){
  if (blockIdx.x >= 512) {
    int i = (blockIdx.x - 512)*256 + threadIdx.x;
    b_all[i] = fuse_b[i];
    return;
  }
  int n = blockIdx.x*4 + (threadIdx.x>>6);
  int lane = threadIdx.x & 63;
  const short* row = Wc + (long)n*1024;
  float acc = 0.f;
  for (int j=lane; j<1024; j+=64) acc += bf2f(row[j])*fuse_b[j];
  #pragma unroll
  for (int m=32;m;m>>=1) acc += __shfl_xor(acc, m, 64);
  if (lane==0) b_all[1024+n] = acc + bc[n];
}

#define GLDS(src, dst) __builtin_amdgcn_global_load_lds( \
    (const __attribute__((address_space(1))) void*)(src), \
    (__attribute__((address_space(3))) void*)(dst), 16, 0, 0)

// ---------- small NT GEMM (128x128 tile, m97 structure): C bf16 = A@B^T ----------
__global__ __launch_bounds__(256, 2)
void gemm_nt_small(const short* __restrict__ Abase, const short* __restrict__ Bbase,
                   short* __restrict__ Cbase,
                   int M, int N, int K, long zA, long zB, long zC)
{
  __shared__ __align__(16) short ldsA[128*32];
  __shared__ __align__(16) short ldsB[128*32];
  const short* A = Abase + (long)blockIdx.z * zA;
  const short* B = Bbase + (long)blockIdx.z * zB;
  const int m0 = blockIdx.x * 128;
  const int n0 = blockIdx.y * 128;
  const int tid = threadIdx.x;
  const int lane = tid & 63;
  const int wv = tid >> 6;
  const int wm = wv >> 1, wn = wv & 1;

  f32x4 acc[4][4];
  #pragma unroll
  for (int i=0;i<4;i++)
    #pragma unroll
    for (int j=0;j<4;j++) acc[i][j] = (f32x4){0.f,0.f,0.f,0.f};

  const int bo0 = wv*1024 + lane*16;
  const int bo1 = bo0 + 4096;
  const int r0 = bo0 >> 6, c0 = bo0 & 63;
  const int r1 = bo1 >> 6, c1 = bo1 & 63;
  const long rsb = (long)K * 2;

  const char* Ab = (const char*)A;
  const char* Bb = (const char*)B;
  char* lA = (char*)&ldsA[0];
  char* lB = (char*)&ldsB[0];

  const int nkt = K >> 5;
  for (int kt = 0; kt < nkt; ++kt) {
    const long kb = (long)kt * 64;
    GLDS(Ab + (long)(m0 + r0)*rsb + kb + c0, lA + wv*1024);
    GLDS(Ab + (long)(m0 + r1)*rsb + kb + c1, lA + 4096 + wv*1024);
    GLDS(Bb + (long)(n0 + r0)*rsb + kb + c0, lB + wv*1024);
    GLDS(Bb + (long)(n0 + r1)*rsb + kb + c1, lB + 4096 + wv*1024);
    __syncthreads();

    s16x8 af[4], bfv[4];
    #pragma unroll
    for (int i=0;i<4;i++)
      af[i] = *(const s16x8*)(lA + (wm*64 + i*16 + (lane&15))*64 + (lane>>4)*16);
    #pragma unroll
    for (int j=0;j<4;j++)
      bfv[j] = *(const s16x8*)(lB + (wn*64 + j*16 + (lane&15))*64 + (lane>>4)*16);

    #pragma unroll
    for (int i=0;i<4;i++)
      #pragma unroll
      for (int j=0;j<4;j++)
        acc[i][j] = __builtin_amdgcn_mfma_f32_16x16x32_bf16(af[i], bfv[j], acc[i][j], 0, 0, 0);
    __syncthreads();
  }

  short* C = Cbase + (long)blockIdx.z * zC;
  #pragma unroll
  for (int j=0;j<4;j++){
    int gn = n0 + wn*64 + j*16 + (lane&15);
    #pragma unroll
    for (int i=0;i<4;i++){
      int gmb = m0 + wm*64 + i*16 + ((lane>>4)*4);
      #pragma unroll
      for (int r=0;r<4;r++)
        C[(long)(gmb+r)*N + gn] = f2bf(acc[i][j][r]);
    }
  }
}

// ---------- main NT GEMM: 256x256 tile, BK=64, 8-phase (T1+T2+T3+T4+T5) ----------
// LDS regions (bytes): A-buf0 @0, A-buf1 @32768, B-buf0 @65536, B-buf1 @98304.
// Full 3-bit swizzle: logical 16B-slot s of row r stored at chunk s^(r&7)
// (conflict-free: 8 consecutive rows at same slot spread over all 8 slots).
// Stage slots/iter (compute t from buf0 ph1-4, t+1 from buf1 ph5-8):
//   ph1: A(t+1)H0->A1    ph2: A(t+1)H1->A1, B(t+2)H0->B0   ph3: B(t+2)H1->B0
//   ph4: VMW4 (drains B(t+1) prev + A(t+1); leaves B(t+2))
//   ph5: A(t+2)H0->A0    ph6: A(t+2)H1->A0, B(t+3)H0->B1   ph7: B(t+3)H1->B1
//   ph8: VMW4 (drains B(t+2) + A(t+2); leaves B(t+3))
// B slack 5.5-7 phases (HBM-safe); A slack ~3 phases (L2-resident via XCD swizzle).
#define MFMA16 __builtin_amdgcn_mfma_f32_16x16x32_bf16
#define VMW4 asm volatile("s_waitcnt vmcnt(4)" ::: "memory")
#define VMW0 asm volatile("s_waitcnt vmcnt(0)" ::: "memory")
#define NOSTAGE ((void)0)

#define PHASE(BUF, Q, STAGE_STMT, VM) { \
  if ((Q)==0) { \
    _Pragma("unroll") \
    for (int j=0;j<4;j++){ bfr[j][0]=ldB(BUF,j,0); bfr[j][1]=ldB(BUF,j,1);} \
  } \
  s16x8 aq0 = ldA(BUF, 2*(Q), 0),   aq1 = ldA(BUF, 2*(Q), 1); \
  s16x8 aq2 = ldA(BUF, 2*(Q)+1, 0), aq3 = ldA(BUF, 2*(Q)+1, 1); \
  STAGE_STMT; \
  asm volatile("" ::: "memory"); \
  __builtin_amdgcn_s_barrier(); \
  asm volatile("s_waitcnt lgkmcnt(0)" ::: "memory"); \
  __builtin_amdgcn_s_setprio(1); \
  _Pragma("unroll") \
  for (int j=0;j<4;j++){ \
    acc[2*(Q)][j]   = MFMA16(aq0, bfr[j][0], acc[2*(Q)][j],   0,0,0); \
    acc[2*(Q)][j]   = MFMA16(aq1, bfr[j][1], acc[2*(Q)][j],   0,0,0); \
    acc[2*(Q)+1][j] = MFMA16(aq2, bfr[j][0], acc[2*(Q)+1][j], 0,0,0); \
    acc[2*(Q)+1][j] = MFMA16(aq3, bfr[j][1], acc[2*(Q)+1][j], 0,0,0); \
  } \
  __builtin_amdgcn_s_setprio(0); \
  VM; \
  asm volatile("" ::: "memory"); \
  __builtin_amdgcn_s_barrier(); \
}

__global__ __launch_bounds__(512, 2)
void gemm_main(const short* __restrict__ A, const short* __restrict__ B,
               float* __restrict__ O, const float* __restrict__ bias,
               int M, int N, int K)
{
  __shared__ __align__(16) char lds[131072];

  const int nbn = N >> 8;
  const int nwg = (M >> 8) * nbn;
  const int cpx = nwg >> 3;
  int bid = blockIdx.x;
  int swz = (bid & 7) * cpx + (bid >> 3);
  const int m0 = (swz / nbn) << 8;
  const int n0 = (swz % nbn) << 8;

  const int tid  = threadIdx.x;
  const int lane = tid & 63;
  const int wid  = tid >> 6;
  const int wm   = wid >> 2;   // 0..1
  const int wn   = wid & 3;    // 0..3
  const long rsb = (long)K * 2;
  const char* Ab = (const char*)A;
  const char* Bb = (const char*)B;

  f32x4 acc[8][4];
  #pragma unroll
  for (int i=0;i<8;i++)
    #pragma unroll
    for (int j=0;j<4;j++) acc[i][j] = (f32x4){0.f,0.f,0.f,0.f};

  // Stage source precompute. Linear LDS dest chunk c = H*1024+sb*512+wid*64+lane;
  // it must receive logical chunk q = c ^ ((c>>3)&7)  (row = c>>3 preserved).
  long srow[2][2]; int scol[2][2]; int sdst[2][2];
  #pragma unroll
  for (int H=0;H<2;H++)
    #pragma unroll
    for (int sb=0;sb<2;sb++){
      int c = H*1024 + sb*512 + wid*64 + lane;
      int q = c ^ ((c>>3)&7);
      srow[H][sb] = (long)(q >> 3);
      scol[H][sb] = (q & 7) << 4;
      sdst[H][sb] = (H*1024 + sb*512 + wid*64) << 4;  // wave-uniform LDS byte base
    }

  auto stage = [&](const char* P, int tr0, int s /*K-tile*/, int RB, int H){
    const long ktb = (long)s << 7;
    GLDS(P + ((long)tr0 + srow[H][0])*rsb + ktb + scol[H][0], lds + RB + sdst[H][0]);
    GLDS(P + ((long)tr0 + srow[H][1])*rsb + ktb + scol[H][1], lds + RB + sdst[H][1]);
  };

  // Read swizzle: row&7 == lane&7 for every fragment read -> per-lane constant.
  const int swx = (lane & 7) << 4;
  auto ldA = [&](int buf, int i, int ks) -> s16x8 {
    int off = (wm*128 + i*16 + (lane&15))*128 + ks*64 + ((lane>>4)<<4);
    off ^= swx;
    return *(const s16x8*)(lds + (buf<<15) + off);
  };
  auto ldB = [&](int buf, int j, int ks) -> s16x8 {
    int off = (wn*64 + j*16 + (lane&15))*128 + ks*64 + ((lane>>4)<<4);
    off ^= swx;
    return *(const s16x8*)(lds + 65536 + (buf<<15) + off);
  };

  s16x8 bfr[4][2];
  const int nkt = K >> 6;  // 64-wide K-tiles (even, >= 4)

  // Prologue: A(0)->A0, B(0)->B0, B(1)->B1; drain A(0),B(0), keep B(1) in flight.
  stage(Ab, m0, 0, 0,     0); stage(Ab, m0, 0, 0,     1);
  stage(Bb, n0, 0, 65536, 0); stage(Bb, n0, 0, 65536, 1);
  stage(Bb, n0, 1, 98304, 0); stage(Bb, n0, 1, 98304, 1);
  VMW4;
  asm volatile("" ::: "memory");
  __builtin_amdgcn_s_barrier();

  for (int it = 0; it < (nkt>>1) - 1; ++it) {
    const int t = it*2;
    PHASE(0, 0, stage(Ab, m0, t+1, 32768, 0), NOSTAGE)
    PHASE(0, 1, (stage(Ab, m0, t+1, 32768, 1), stage(Bb, n0, t+2, 65536, 0)), NOSTAGE)
    PHASE(0, 2, stage(Bb, n0, t+2, 65536, 1), NOSTAGE)
    PHASE(0, 3, NOSTAGE, VMW4)
    PHASE(1, 0, stage(Ab, m0, t+2, 0, 0), NOSTAGE)
    PHASE(1, 1, (stage(Ab, m0, t+2, 0, 1), stage(Bb, n0, t+3, 98304, 0)), NOSTAGE)
    PHASE(1, 2, stage(Bb, n0, t+3, 98304, 1), NOSTAGE)
    PHASE(1, 3, NOSTAGE, VMW4)
  }
  {
    const int t = nkt - 2;
    PHASE(0, 0, stage(Ab, m0, t+1, 32768, 0), NOSTAGE)
    PHASE(0, 1, stage(Ab, m0, t+1, 32768, 1), NOSTAGE)
    PHASE(0, 2, NOSTAGE, NOSTAGE)
    PHASE(0, 3, NOSTAGE, VMW0)
    PHASE(1, 0, NOSTAGE, NOSTAGE)
    PHASE(1, 1, NOSTAGE, NOSTAGE)
    PHASE(1, 2, NOSTAGE, NOSTAGE)
    PHASE(1, 3, NOSTAGE, NOSTAGE)
  }

  // Epilogue: fp32 + bias, scatter by output region (text | image | fused).
  const long BD = (long)M * 1024L;
  #pragma unroll
  for (int j=0;j<4;j++){
    int gn = n0 + wn*64 + j*16 + (lane&15);
    float bb = bias[gn];
    int region = gn >> 10;
    long rbase = (region==0) ? 2*BD : ((region==1) ? 0L : BD);
    int col = gn & 1023;
    #pragma unroll
    for (int i=0;i<8;i++){
      int gr = m0 + wm*128 + i*16 + ((lane>>4)<<2);
      #pragma unroll
      for (int r=0;r<4;r++)
        O[rbase + (long)(gr+r)*1024 + col] = acc[i][j][r] + bb;
    }
  }
}

extern "C" void kernel_launch(void* const* d_in, const int* in_sizes, int n_in,
                              void* d_out, int out_size, void* d_ws, size_t ws_size,
                              hipStream_t stream) {
  const float* text    = (const float*)d_in[0];
  const float* image   = (const float*)d_in[1];
  const float* fuse_w  = (const float*)d_in[2];
  const float* fuse_b  = (const float*)d_in[3];
  const float* t_in_w  = (const float*)d_in[4];
  const float* t_in_b  = (const float*)d_in[5];
  const float* t_out_w = (const float*)d_in[6];
  const float* t_out_b = (const float*)d_in[7];
  const float* i_in_w  = (const float*)d_in[8];
  const float* i_in_b  = (const float*)d_in[9];
  const float* i_out_w = (const float*)d_in[10];
  const float* i_out_b = (const float*)d_in[11];
  float* out = (float*)d_out;

  const long DD = 1024L*1024L;
  char* ws = (char*)d_ws;
  short* s_bf    = (short*)ws; ws += 16384L*1024*2;
  short* W_all   = (short*)ws; ws += 3*DD*2;      // rows: [fuse_w; Wt2; Wi2]
  short* wvT     = (short*)ws; ws += 2*DD*2;      // [wvT_t; wvT_i]
  short* fuse_wT = (short*)ws; ws += DD*2;
  short* outw_st = (short*)ws; ws += 2*DD*2;      // [t_out_w; i_out_w] bf16
  short* Wc_st   = (short*)ws; ws += 2*DD*2;      // [Wc_t; Wc_i]
  float* bc      = (float*)ws; ws += 2048*4;
  float* b_all   = (float*)ws; ws += 3072*4;

  // prep
  k_addcvt<<<8192, 256, 0, stream>>>(text, image, s_bf);
  k_cvt3<<<dim3(1024,3), 256, 0, stream>>>(fuse_w, W_all,
                                           t_out_w, outw_st,
                                           i_out_w, outw_st + DD);
  k_transcvt3<<<dim3(32,32,3), dim3(32,8), 0, stream>>>(t_in_w + 2*DD, wvT,
                                                        i_in_w + 2*DD, wvT + DD,
                                                        fuse_w, fuse_wT);
  k_bias1<<<dim3(256,2), 256, 0, stream>>>(t_out_w, t_in_b + 2048, t_out_b,
                                           i_out_w, i_in_b + 2048, i_out_b, bc);

  // Wc_z = out_w_z @ wv_z
  gemm_nt_small<<<dim3(8,8,2), 256, 0, stream>>>(outw_st, wvT, Wc_st,
                                                 1024, 1024, 1024, DD, DD, DD);
  // b_all[1024..3072) = Wc @ fuse_b + bc ; b_all[0..1024) = fuse_b
  k_bias2c<<<516, 256, 0, stream>>>(Wc_st, fuse_b, bc, b_all);
  // [Wt2; Wi2] = Wc @ fuse_w
  gemm_nt_small<<<dim3(16,8,1), 256, 0, stream>>>(Wc_st, fuse_wT, W_all + DD,
                                                  2048, 1024, 1024, 0, 0, 0);
  // main: C = s @ W_all.T + b_all, scatter into d_out
  gemm_main<<<dim3(768), 512, 0, stream>>>(s_bf, W_all, out, b_all, 16384, 3072, 1024);
}